// Round 7
// baseline (73.880 us; speedup 1.0000x reference)
//
#include <hip/hip_runtime.h>
#include <hip/hip_bf16.h>

// SioConv: out[b,i,d] = Re(h[i]) where
//   a[b,l,d] = (re,im) * rsqrt(m2) * exp(-m2),  (re,im) = x[b,l,:] @ W_a rows 2d/2d+1
//   g[i] = a_i * (x_hat[i] + g[i+1])   (backward scan, g[L]=0)
//   out[i] = Re(g[i]) + Re(x_hat[i-1]) (i>=1), out[L-1] += x[b,L-1,d]
//   x_hat[0] = h0 (complex), x_hat[k] = x[b,k-1,d] (real)
//
// Budget model (R2..R6 algebra): harness-fixed floor ~62us (40us ws-poison
// fill at HBM ceiling + ~22us restores/gaps); gemm ~5.5us, scan ~1.5us.
// R7: gemm-v6 — x moves from LDS to the scalar pipe. Wave = 64 d-lanes x
//     2 uniform l-rows (readfirstlane) -> x via s_load; W staged as one
//     contiguous 128-row / 128KB LDS slice (XOR-swizzled cols, 0-conflict
//     pattern per R6 counters). Per k4: 2 ds_read_b128 (was 4) + 2 s_load
//     + 16 FMA. LDS pipe 2.6us, VALU 3.4us (overlap) + ~1us staging.
// Scan unchanged (R6).

constexpr int B = 2, L = 256, D = 256, K = 256;
constexpr int PADW = 260;     // LDS row stride in floats (16B-aligned)

// grid (D/64, L/8, B) = 256 blocks, 256 threads = 4 waves.
__global__ __launch_bounds__(256) void gemm_a_kernel(
    const float* __restrict__ x,    // [B, L, K]
    const float* __restrict__ W,    // [2D, K]
    float2* __restrict__ aT)        // [B, D, L]  (ws, transposed)
{
    const int dq = blockIdx.x;            // d-quad: d0 = dq*64
    const int lt = blockIdx.y;            // l0 = lt*8
    const int b  = blockIdx.z;
    const int t  = threadIdx.x;           // 0..255
    const int d0 = dq * 64;

    __shared__ float ws[128][PADW];       // 133 KB

    // Stage W rows 2*d0 .. 2*d0+127 (contiguous 128 KB): 8192 float4,
    // 32 per thread, coalesced. Logical col c4 of row r -> physical
    // c4 ^ ((r>>1)&7) (same swizzle as R6; measured 0 conflicts).
    {
        const float4* src = (const float4*)(W + (size_t)(2 * d0) * K);
#pragma unroll
        for (int j = 0; j < 32; ++j) {
            const int g = j * 256 + t;
            const int row = g >> 6, c4 = g & 63;
            *(float4*)&ws[row][(c4 ^ ((row >> 1) & 7)) * 4] = src[g];
        }
    }
    __syncthreads();

    const int dl = t & 63;                                        // lane -> d
    const int wv = __builtin_amdgcn_readfirstlane(t >> 6);        // wave id (SGPR)
    const int l0 = lt * 8 + wv * 2;                               // wave-uniform
    const int sw = dl & 7;

    const float* xr0 = x + (size_t)(b * L + l0) * K;              // uniform base
    const float* xr1 = xr0 + K;

    float re0 = 0.f, im0 = 0.f, re1 = 0.f, im1 = 0.f;
#pragma unroll 4
    for (int k4 = 0; k4 < K / 4; ++k4) {
        const int kc = (k4 ^ sw) * 4;                             // swizzled col
        const float4 w0 = *(const float4*)&ws[2 * dl][kc];
        const float4 w1 = *(const float4*)&ws[2 * dl + 1][kc];
        const float4 x0 = *(const float4*)(xr0 + k4 * 4);         // uniform -> s_load
        const float4 x1 = *(const float4*)(xr1 + k4 * 4);         // uniform -> s_load
        re0 += x0.x * w0.x + x0.y * w0.y + x0.z * w0.z + x0.w * w0.w;
        im0 += x0.x * w1.x + x0.y * w1.y + x0.z * w1.z + x0.w * w1.w;
        re1 += x1.x * w0.x + x1.y * w0.y + x1.z * w0.z + x1.w * w0.w;
        im1 += x1.x * w1.x + x1.y * w1.y + x1.z * w1.z + x1.w * w1.w;
    }

    const int d = d0 + dl;
#pragma unroll
    for (int i = 0; i < 2; ++i) {
        const float re = i ? re1 : re0, im = i ? im1 : im0;
        const float m2 = re * re + im * im;
        const float s  = rsqrtf(m2) * expf(-m2);
        // transposed store [b,d,l]; strided but only 512 8-B txns/block
        aT[((size_t)b * D + d) * L + (l0 + i)] = make_float2(re * s, im * s);
    }
}

// One block per (b,d) column; thread i owns scan position i. (unchanged R6)
__global__ __launch_bounds__(256) void scan_h_kernel(
    const float* __restrict__ x,    // [B, L, D]
    const float2* __restrict__ aT,  // [B, D, L]
    const float* __restrict__ h0r,  // [D]
    const float* __restrict__ h0i,  // [D]
    float* __restrict__ out)        // [B, L, D]
{
    const int b = blockIdx.x >> 8;
    const int d = blockIdx.x & 255;
    const int i = threadIdx.x;

    __shared__ float4 Ms[L];              // 4 KB
    __shared__ float  xcol[L];            // 1 KB

    const size_t colbase = (size_t)b * L * D + d;

    const float2 ai = aT[((size_t)b * D + d) * L + i];   // coalesced
    xcol[i] = x[colbase + (size_t)i * D];
    __syncthreads();

    float xr, xi;
    if (i == 0) { xr = h0r[d]; xi = h0i[d]; }
    else        { xr = xcol[i - 1]; xi = 0.f; }

    // f_i = (A = a_i, B = a_i * xhat_i)
    float Ar = ai.x, Ai = ai.y;
    float Br = ai.x * xr - ai.y * xi;
    float Bi = ai.x * xi + ai.y * xr;

#pragma unroll
    for (int o = 1; o < L; o <<= 1) {
        Ms[i] = make_float4(Ar, Ai, Br, Bi);
        __syncthreads();
        if (i + o < L) {
            const float4 n = Ms[i + o];
            const float nAr = Ar * n.x - Ai * n.y;
            const float nAi = Ar * n.y + Ai * n.x;
            const float nBr = Ar * n.z - Ai * n.w + Br;
            const float nBi = Ar * n.w + Ai * n.z + Bi;
            Ar = nAr; Ai = nAi; Br = nBr; Bi = nBi;
        }
        __syncthreads();
    }

    float o_val = Br;
    if (i >= 2)      o_val += xcol[i - 2];
    else if (i == 1) o_val += h0r[d];
    if (i == L - 1)  o_val += xcol[L - 1];
    out[colbase + (size_t)i * D] = o_val;
}

extern "C" void kernel_launch(void* const* d_in, const int* in_sizes, int n_in,
                              void* d_out, int out_size, void* d_ws, size_t ws_size,
                              hipStream_t stream) {
    const float* x    = (const float*)d_in[0];   // B*L*D
    const float* W_a  = (const float*)d_in[1];   // 2D*D
    const float* h0r  = (const float*)d_in[2];   // D
    const float* h0i  = (const float*)d_in[3];   // D
    float* out = (float*)d_out;
    float2* aT = (float2*)d_ws;                  // B*D*L float2 = 1 MiB

    gemm_a_kernel<<<dim3(D / 64, L / 8, B), dim3(256), 0, stream>>>(x, W_a, aT);
    scan_h_kernel<<<dim3(B * D), dim3(256), 0, stream>>>(x, aT, h0r, h0i, out);
}

// Round 8
// 70.573 us; speedup vs baseline: 1.0469x; 1.0469x over previous
//
#include <hip/hip_runtime.h>
#include <hip/hip_bf16.h>

// SioConv: out[b,i,d] = Re(h[i]) where
//   a[b,l,d] = (re,im) * rsqrt(m2) * exp(-m2),  (re,im) = x[b,l,:] @ W_a rows 2d/2d+1
//   g[i] = a_i * (x_hat[i] + g[i+1])   (backward scan, g[L]=0)
//   out[i] = Re(g[i]) + Re(x_hat[i-1]) (i>=1), out[L-1] += x[b,L-1,d]
//   x_hat[0] = h0 (complex), x_hat[k] = x[b,k-1,d] (real)
//
// R8: R6 gemm (best measured, 69.4us) with ONE change: x no longer staged in
//     LDS — read directly from global. The 16 dgrp-lanes share each x address
//     (4 distinct rows/wave-load -> L1 broadcast; x[b]=256KB L2-resident), so
//     the VMEM pipe carries x while LDS carries only W: LDS-pipe work halves
//     (1024 -> 512 b128/CU, 5.1 -> 2.6us) and the pipes overlap.
//     R7 post-mortem: 133KB LDS tile killed occupancy + quadrupled W staging;
//     this keeps R6's 33KB tile / 256-block grid / swizzle exactly.
// Scan unchanged (R6).

constexpr int B = 2, L = 256, D = 256, K = 256;
constexpr int TL = 32;        // l-rows per gemm block
constexpr int TD = 16;        // d-outputs per gemm block (32 W rows)
constexpr int PADW = 260;     // LDS row stride in floats (16B-aligned)

__global__ __launch_bounds__(256) void gemm_a_kernel(
    const float* __restrict__ x,    // [B, L, K]
    const float* __restrict__ W,    // [2D, K]
    float2* __restrict__ aT)        // [B, D, L]  (ws, transposed)
{
    const int dt = blockIdx.x;            // 0..15
    const int lt = blockIdx.y;            // 0..7
    const int b  = blockIdx.z;
    const int t  = threadIdx.x;           // 0..255
    const int l0 = lt * TL;
    const int d0 = dt * TD;

    __shared__ float ws[2 * TD][PADW];    // 33.3 KB (W only)

    // Stage W rows 2*d0 .. 2*d0+31 (contiguous 32 KB), XOR-swizzled columns:
    // logical c4 of row r lives at physical c4 ^ ((r>>1)&7). (R6: 0 conflicts)
    {
        const float4* src = (const float4*)(W + (size_t)(2 * d0) * K);
#pragma unroll
        for (int j = 0; j < 8; ++j) {
            const int g = j * 256 + t;
            const int row = g >> 6, c4 = g & 63;
            *(float4*)&ws[row][(c4 ^ ((row >> 1) & 7)) * 4] = src[g];
        }
    }
    __syncthreads();

    const int dgrp = t & 15;              // d within tile
    const int lgrp = t >> 4;              // 0..15 -> l pair
    const int sw   = dgrp & 7;

    // x rows read straight from global: 16 lanes/group share the address
    // (broadcast), 4 distinct rows per wave load, L1/L2-served.
    const float4* x0p = (const float4*)(x + (size_t)(b * L + l0 + 2 * lgrp) * K);
    const float4* x1p = x0p + K / 4;

    float rr0 = 0.f, ii0 = 0.f, rr1 = 0.f, ii1 = 0.f;
#pragma unroll 8
    for (int k4 = 0; k4 < K / 4; ++k4) {
        const int kc = (k4 ^ sw) * 4;     // physical column of logical k4
        const float4 w0  = *(const float4*)&ws[2 * dgrp][kc];
        const float4 w1  = *(const float4*)&ws[2 * dgrp + 1][kc];
        const float4 xv0 = x0p[k4];       // VMEM pipe (was LDS)
        const float4 xv1 = x1p[k4];
        rr0 += xv0.x * w0.x + xv0.y * w0.y + xv0.z * w0.z + xv0.w * w0.w;
        ii0 += xv0.x * w1.x + xv0.y * w1.y + xv0.z * w1.z + xv0.w * w1.w;
        rr1 += xv1.x * w0.x + xv1.y * w0.y + xv1.z * w0.z + xv1.w * w0.w;
        ii1 += xv1.x * w1.x + xv1.y * w1.y + xv1.z * w1.z + xv1.w * w1.w;
    }

    const int d = d0 + dgrp;
#pragma unroll
    for (int i = 0; i < 2; ++i) {
        const float re = i ? rr1 : rr0, im = i ? ii1 : ii0;
        const float m2 = re * re + im * im;
        const float s  = rsqrtf(m2) * expf(-m2);
        // transposed store [b,d,l]; strided across lanes but tiny total txns
        aT[((size_t)b * D + d) * L + (l0 + 2 * lgrp + i)] = make_float2(re * s, im * s);
    }
}

// One block per (b,d) column; thread i owns scan position i. (unchanged R6)
__global__ __launch_bounds__(256) void scan_h_kernel(
    const float* __restrict__ x,    // [B, L, D]
    const float2* __restrict__ aT,  // [B, D, L]
    const float* __restrict__ h0r,  // [D]
    const float* __restrict__ h0i,  // [D]
    float* __restrict__ out)        // [B, L, D]
{
    const int b = blockIdx.x >> 8;
    const int d = blockIdx.x & 255;
    const int i = threadIdx.x;

    __shared__ float4 Ms[L];              // 4 KB
    __shared__ float  xcol[L];            // 1 KB

    const size_t colbase = (size_t)b * L * D + d;

    const float2 ai = aT[((size_t)b * D + d) * L + i];   // coalesced
    xcol[i] = x[colbase + (size_t)i * D];
    __syncthreads();

    float xr, xi;
    if (i == 0) { xr = h0r[d]; xi = h0i[d]; }
    else        { xr = xcol[i - 1]; xi = 0.f; }

    // f_i = (A = a_i, B = a_i * xhat_i)
    float Ar = ai.x, Ai = ai.y;
    float Br = ai.x * xr - ai.y * xi;
    float Bi = ai.x * xi + ai.y * xr;

#pragma unroll
    for (int o = 1; o < L; o <<= 1) {
        Ms[i] = make_float4(Ar, Ai, Br, Bi);
        __syncthreads();
        if (i + o < L) {
            const float4 n = Ms[i + o];
            const float nAr = Ar * n.x - Ai * n.y;
            const float nAi = Ar * n.y + Ai * n.x;
            const float nBr = Ar * n.z - Ai * n.w + Br;
            const float nBi = Ar * n.w + Ai * n.z + Bi;
            Ar = nAr; Ai = nAi; Br = nBr; Bi = nBi;
        }
        __syncthreads();
    }

    float o_val = Br;
    if (i >= 2)      o_val += xcol[i - 2];
    else if (i == 1) o_val += h0r[d];
    if (i == L - 1)  o_val += xcol[L - 1];
    out[colbase + (size_t)i * D] = o_val;
}

extern "C" void kernel_launch(void* const* d_in, const int* in_sizes, int n_in,
                              void* d_out, int out_size, void* d_ws, size_t ws_size,
                              hipStream_t stream) {
    const float* x    = (const float*)d_in[0];   // B*L*D
    const float* W_a  = (const float*)d_in[1];   // 2D*D
    const float* h0r  = (const float*)d_in[2];   // D
    const float* h0i  = (const float*)d_in[3];   // D
    float* out = (float*)d_out;
    float2* aT = (float2*)d_ws;                  // B*D*L float2 = 1 MiB

    gemm_a_kernel<<<dim3(D / TD, L / TL, B), dim3(256), 0, stream>>>(x, W_a, aT);
    scan_h_kernel<<<dim3(B * D), dim3(256), 0, stream>>>(x, aT, h0r, h0i, out);
}

// Round 9
// 69.063 us; speedup vs baseline: 1.0697x; 1.0219x over previous
//
#include <hip/hip_runtime.h>
#include <hip/hip_bf16.h>

// SioConv: out[b,i,d] = Re(h[i]) where
//   a[b,l,d] = (re,im) * rsqrt(m2) * exp(-m2),  (re,im) = x[b,l,:] @ W_a rows 2d/2d+1
//   g[i] = a_i * (x_hat[i] + g[i+1])   (backward scan, g[L]=0)
//   out[i] = Re(g[i]) + Re(x_hat[i-1]) (i>=1), out[L-1] += x[b,L-1,d]
//   x_hat[0] = h0 (complex), x_hat[k] = x[b,k-1,d] (real)
//
// R9: REVERT to R6 (measured best, 69.43us). R7 (x->scalar pipe, 133KB LDS:
//     +4.4us, occupancy+staging regression) and R8 (x->VMEM pipe: +1.1us,
//     VMEM issue+latency not hidden) both lost to this structure. The
//     remaining controllable time (~7us kernels over a ~62us harness floor:
//     40us d_ws poison-fill at 84% HBM peak + restore/replay gaps) is within
//     fill-dispatch run-to-run variance; this is the practical optimum.
//  gemm: tile 32l x 16d, 256 blocks, 2-way l register blocking, W-tile
//        XOR-swizzled (col ^ (dpair&7)) -> 0 measured bank conflicts,
//        a stored TRANSPOSED [b,d,l] so the scan's a-load coalesces.
//  scan: 512-block Hillis-Steele suffix scan over complex affine maps,
//        x column staged once into LDS.

constexpr int B = 2, L = 256, D = 256, K = 256;
constexpr int TL = 32;        // l-rows per gemm block
constexpr int TD = 16;        // d-outputs per gemm block (32 W rows)
constexpr int PADW = 260;     // LDS row stride in floats (16B-aligned)

__global__ __launch_bounds__(256) void gemm_a_kernel(
    const float* __restrict__ x,    // [B, L, K]
    const float* __restrict__ W,    // [2D, K]
    float2* __restrict__ aT)        // [B, D, L]  (ws, transposed)
{
    const int dt = blockIdx.x;            // 0..15
    const int lt = blockIdx.y;            // 0..7
    const int b  = blockIdx.z;
    const int t  = threadIdx.x;           // 0..255
    const int l0 = lt * TL;
    const int d0 = dt * TD;

    __shared__ float xs[TL][PADW];        // 33.3 KB
    __shared__ float ws[2 * TD][PADW];    // 33.3 KB

    // Stage x rows l0..l0+31 (32 KB contiguous): 2048 float4, 8/thread.
    {
        const float4* src = (const float4*)(x + (size_t)(b * L + l0) * K);
#pragma unroll
        for (int j = 0; j < 8; ++j) {
            const int g = j * 256 + t;
            const int row = g >> 6, c4 = g & 63;
            *(float4*)&xs[row][c4 * 4] = src[g];
        }
    }
    // Stage W rows 2*d0 .. 2*d0+31, XOR-swizzled columns: logical c4 of row r
    // lives at physical c4 ^ ((r>>1)&7).
    {
        const float4* src = (const float4*)(W + (size_t)(2 * d0) * K);
#pragma unroll
        for (int j = 0; j < 8; ++j) {
            const int g = j * 256 + t;
            const int row = g >> 6, c4 = g & 63;
            *(float4*)&ws[row][(c4 ^ ((row >> 1) & 7)) * 4] = src[g];
        }
    }
    __syncthreads();

    const int dgrp = t & 15;              // d within tile
    const int lgrp = t >> 4;              // 0..15 -> l pair
    const int sw   = dgrp & 7;            // swizzle key for this thread's W rows

    float rr0 = 0.f, ii0 = 0.f, rr1 = 0.f, ii1 = 0.f;
#pragma unroll 8
    for (int k4 = 0; k4 < K / 4; ++k4) {
        const int kc = (k4 ^ sw) * 4;     // physical column of logical k4
        const float4 w0  = *(const float4*)&ws[2 * dgrp][kc];
        const float4 w1  = *(const float4*)&ws[2 * dgrp + 1][kc];
        const float4 xv0 = *(const float4*)&xs[2 * lgrp][k4 * 4];      // broadcast
        const float4 xv1 = *(const float4*)&xs[2 * lgrp + 1][k4 * 4];  // broadcast
        rr0 += xv0.x * w0.x + xv0.y * w0.y + xv0.z * w0.z + xv0.w * w0.w;
        ii0 += xv0.x * w1.x + xv0.y * w1.y + xv0.z * w1.z + xv0.w * w1.w;
        rr1 += xv1.x * w0.x + xv1.y * w0.y + xv1.z * w0.z + xv1.w * w0.w;
        ii1 += xv1.x * w1.x + xv1.y * w1.y + xv1.z * w1.z + xv1.w * w1.w;
    }

    const int d = d0 + dgrp;
#pragma unroll
    for (int i = 0; i < 2; ++i) {
        const float re = i ? rr1 : rr0, im = i ? ii1 : ii0;
        const float m2 = re * re + im * im;
        const float s  = rsqrtf(m2) * expf(-m2);
        // transposed store [b,d,l]; strided across lanes but tiny total txns
        aT[((size_t)b * D + d) * L + (l0 + 2 * lgrp + i)] = make_float2(re * s, im * s);
    }
}

// One block per (b,d) column; thread i owns scan position i.
__global__ __launch_bounds__(256) void scan_h_kernel(
    const float* __restrict__ x,    // [B, L, D]
    const float2* __restrict__ aT,  // [B, D, L]
    const float* __restrict__ h0r,  // [D]
    const float* __restrict__ h0i,  // [D]
    float* __restrict__ out)        // [B, L, D]
{
    const int b = blockIdx.x >> 8;
    const int d = blockIdx.x & 255;
    const int i = threadIdx.x;

    __shared__ float4 Ms[L];              // 4 KB
    __shared__ float  xcol[L];            // 1 KB: xcol[l] = x[b,l,d]

    const size_t colbase = (size_t)b * L * D + d;

    // Coalesced a-load (transposed layout) + one strided x column read.
    const float2 ai = aT[((size_t)b * D + d) * L + i];
    xcol[i] = x[colbase + (size_t)i * D];
    __syncthreads();

    float xr, xi;
    if (i == 0) { xr = h0r[d]; xi = h0i[d]; }
    else        { xr = xcol[i - 1]; xi = 0.f; }

    // f_i = (A = a_i, B = a_i * xhat_i)
    float Ar = ai.x, Ai = ai.y;
    float Br = ai.x * xr - ai.y * xi;
    float Bi = ai.x * xi + ai.y * xr;

#pragma unroll
    for (int o = 1; o < L; o <<= 1) {
        Ms[i] = make_float4(Ar, Ai, Br, Bi);
        __syncthreads();
        if (i + o < L) {
            const float4 n = Ms[i + o];
            const float nAr = Ar * n.x - Ai * n.y;
            const float nAi = Ar * n.y + Ai * n.x;
            const float nBr = Ar * n.z - Ai * n.w + Br;
            const float nBi = Ar * n.w + Ai * n.z + Bi;
            Ar = nAr; Ai = nAi; Br = nBr; Bi = nBi;
        }
        __syncthreads();
    }

    // g_i = B_i (g[L]=0). Epilogue from LDS copies.
    float o_val = Br;
    if (i >= 2)      o_val += xcol[i - 2];
    else if (i == 1) o_val += h0r[d];
    if (i == L - 1)  o_val += xcol[L - 1];
    out[colbase + (size_t)i * D] = o_val;
}

extern "C" void kernel_launch(void* const* d_in, const int* in_sizes, int n_in,
                              void* d_out, int out_size, void* d_ws, size_t ws_size,
                              hipStream_t stream) {
    const float* x    = (const float*)d_in[0];   // B*L*D
    const float* W_a  = (const float*)d_in[1];   // 2D*D
    const float* h0r  = (const float*)d_in[2];   // D
    const float* h0i  = (const float*)d_in[3];   // D
    float* out = (float*)d_out;
    float2* aT = (float2*)d_ws;                  // B*D*L float2 = 1 MiB

    gemm_a_kernel<<<dim3(D / TD, L / TL, B), dim3(256), 0, stream>>>(x, W_a, aT);
    scan_h_kernel<<<dim3(B * D), dim3(256), 0, stream>>>(x, aT, h0r, h0i, out);
}